// Round 8
// baseline (517.348 us; speedup 1.0000x reference)
//
#include <hip/hip_runtime.h>
#include <hip/hip_cooperative_groups.h>
#include <cstdint>

// ---------------------------------------------------------------------------
// dysOpt: Davis-Yin splitting, 262144 rows x 64 vars, dynamic T.
//
// x20 u-space iteration (U = 20*(z + C), CC = 20*C):
//   m'  = med3(U, CC, CC+20)      (= 20*(clamp(z,0,1)+C)), computed IN PLACE
//   U+  = K1*m' + nc[j]           (nc = -c, stored negated)
//   Sx  = 0.05*(Sm' - 64*CC) ; t = K2*Sx - R
//   corr20 = t*(20/64) - 10 ; R+ = R - Sx + 32 ; CC+ = K1*CC + corr20
//
// ROUND-18 (kill pass2's structure; r17 post-mortem):
//  * pass1 = 237us at VALU-issue roofline (VALUBusy 103, VGPR 32). Probe
//    rework landed as predicted (total 386->369). Residue ~117us: probe 15
//    + pass2 ~100 vs a ~40us floor. pass2's overhead IS the structure:
//    kernel-boundary-as-grid-barrier forces zst round-trip (66W+132R MB),
//    a 3rd launch, and full re-init of all 16384 waves.
//  * Fix: REAL grid barrier via hipLaunchCooperativeKernel (explicitly
//    supported per the platform guide). 2048 blocks x 256 thr = 8192 waves
//    (exactly 8 blocks/CU at VGPR<=64, pinned by waves_per_eu(8,8); state
//    is 32 VGPR). Each wave solves TWO row-groups sequentially (same
//    2-round pipelining pass1 already had -> phase-A wall unchanged):
//      A: g0 solve -> checkpoint z(ib0) (33MB, same-wave, L3-hot);
//         g1 solve -> state STAYS IN REGISTERS (36 live < 64 budget)
//      grid.sync(); T final
//      B: finish g1 fully in-register (zero reload); reload g0 from ckpt.
//    Deletes: pass2 launch, TrArr, 33MB zst write, 66MB reload, half the
//    re-init. Expected total 369 -> ~300-320.
//  * Hedge: if hipLaunchCooperativeKernel errors, fall back to the r16
//    pass1+pass2 path (kept verbatim below) => worst case ~369.
//  * probe kernel BYTE-IDENTICAL to r17.
//
// Check (per row): 400*||dz||^2 = q2 - 2*dCC*q1 + 64*dCC^2 <= 0.04.
// ---------------------------------------------------------------------------

#ifndef JAX_PARTITIONABLE
#define JAX_PARTITIONABLE 1
#endif

namespace cg = cooperative_groups;

#define BATCHN 262144
#define MAXIT  200

#define PROBE_ROWS 8192
// probe layout P: 4 rows/wave, 16 lanes/row, 4 elems/lane
#define RPW_P  4
#define PROBE_WAVES_P (PROBE_ROWS / RPW_P)  // 2048

#define NWAVES_A 16384                      // workspace offset compat (r10)

// layout D (pass1/pass2/fused): 16 rows/wave, 4 lanes/row, 16 elems/lane
#define RPW_D  16
#define NWAVES_D (BATCHN / RPW_D)           // 16384
#define FUSED_WAVES (NWAVES_D / 2)          // 8192 waves, 2 groups each
#define FUSED_BLOCKS (FUSED_WAVES / 4)      // 2048 blocks x 256 thr

#define K1 0.9975f   // 1 - a^2
#define K2 1.9975f   // 2 - a^2

typedef float v2f __attribute__((ext_vector_type(2)));

__device__ __forceinline__ void tf2x32(uint32_t x0, uint32_t x1,
                                       uint32_t& o0, uint32_t& o1) {
  const uint32_t k0 = 0u, k1 = 1u;                 // jax.random.key(1) -> [0,1]
  const uint32_t k2 = 0x1BD11BDAu ^ k0 ^ k1;
  x0 += k0; x1 += k1;
#define TFR(r) { x0 += x1; x1 = (x1 << (r)) | (x1 >> (32 - (r))); x1 ^= x0; }
  TFR(13) TFR(15) TFR(26) TFR(6)   x0 += k1; x1 += k2 + 1u;
  TFR(17) TFR(29) TFR(16) TFR(24)  x0 += k2; x1 += k0 + 2u;
  TFR(13) TFR(15) TFR(26) TFR(6)   x0 += k0; x1 += k1 + 3u;
  TFR(17) TFR(29) TFR(16) TFR(24)  x0 += k1; x1 += k2 + 4u;
  TFR(13) TFR(15) TFR(26) TFR(6)   x0 += k2; x1 += k0 + 5u;
#undef TFR
  o0 = x0; o1 = x1;
}

__device__ __forceinline__ float z0_at(uint32_t f) {
  uint32_t b;
#if JAX_PARTITIONABLE
  uint32_t o0, o1;
  tf2x32(0u, f, o0, o1);
  b = o0 ^ o1;
#else
  const uint32_t H = 8388608u;
  uint32_t lo = (f < H) ? f : (f - H);
  uint32_t o0, o1;
  tf2x32(lo, lo + H, o0, o1);
  b = (f < H) ? o0 : o1;
#endif
  return __uint_as_float((b >> 9) | 0x3f800000u) - 1.0f;
}

// DPP cross-lane add: v += v(lane DPP-selected). Pure VALU.
template <int CTRL>
__device__ __forceinline__ float dpp_add(float v) {
  int s = __builtin_amdgcn_mov_dpp(__float_as_int(v), CTRL, 0xF, 0xF, true);
  return v + __int_as_float(s);
}

// 4-lane row reduction (row = one quad), all-VALU (layout D)
__device__ __forceinline__ float reduce4(float v) {
  v = dpp_add<0xB1>(v);    // quad_perm [1,0,3,2] : xor 1
  v = dpp_add<0x4E>(v);    // quad_perm [2,3,0,1] : xor 2
  return v;
}

// packed DPP add for a v2f (two mov_dpp + one pk_add)
template <int CTRL>
__device__ __forceinline__ v2f dpp_addv(v2f v) {
  int sx = __builtin_amdgcn_mov_dpp(__float_as_int(v.x), CTRL, 0xF, 0xF, true);
  int sy = __builtin_amdgcn_mov_dpp(__float_as_int(v.y), CTRL, 0xF, 0xF, true);
  v2f s;
  s.x = __int_as_float(sx);
  s.y = __int_as_float(sy);
  return v + s;
}

// 16-lane row sum of BOTH v2f components (probe): xor1, xor2, ror4, ror8.
__device__ __forceinline__ v2f reduce16v(v2f v) {
  v = dpp_addv<0xB1>(v);     // quad_perm xor 1
  v = dpp_addv<0x4E>(v);     // quad_perm xor 2
  v = dpp_addv<0x124>(v);    // row_ror:4
  v = dpp_addv<0x128>(v);    // row_ror:8
  return v;
}

// ===========================================================================
// probe — 2048 waves (2/SIMD), packed math, single packed reduction/iter
// BYTE-IDENTICAL to r17.
// ===========================================================================
__global__ __launch_bounds__(256, 4) void dys_probe(
    const float* __restrict__ cost, int* __restrict__ Tsample) {
  const int lane = threadIdx.x & 63;
  const int wid  = threadIdx.x >> 6;
  const int gw = blockIdx.x * 4 + wid;
  const int base = (gw * RPW_P + (lane >> 4)) * 64 + (lane & 15) * 4;

  const v2f K1p = {K1, K1};
  const float4 cq = *(const float4*)(cost + base);
  v2f nc0, nc1;
  nc0.x = -cq.x; nc0.y = -cq.y; nc1.x = -cq.z; nc1.y = -cq.w;

  const float z0 = z0_at((uint32_t)(base + 0));
  const float z1 = z0_at((uint32_t)(base + 1));
  const float z2 = z0_at((uint32_t)(base + 2));
  const float z3 = z0_at((uint32_t)(base + 3));
  v2f U0, U1;
  U0.x = 20.0f * z0; U0.y = 20.0f * z1;
  U1.x = 20.0f * z2; U1.y = 20.0f * z3;

  v2f zc;                                   // {Sz partial, Sc partial}
  zc.x = (z0 + z1) + (z2 + z3);
  zc.y = (cq.x + cq.y) + (cq.z + cq.w);
  zc = reduce16v(zc);                       // {Sz, Sc} over the row
  float R   = __builtin_fmaf(0.05f, zc.y, zc.x);   // Sz + a*Sc
  const float Snc = -zc.y;                  // sum of nc over the row
  float SU  = 20.0f * zc.x;                 // sum of U over the row
  float CC = 0.0f;

  int ib = MAXIT;
  for (int i = 1; i <= MAXIT; ++i) {
    const float Ch = CC + 20.0f;
    v2f sp, q2v = {0.0f, 0.0f};
    v2f m2, un2, d2;
    // pair 0
    m2.x = __builtin_amdgcn_fmed3f(U0.x, CC, Ch);
    m2.y = __builtin_amdgcn_fmed3f(U0.y, CC, Ch);
    sp = m2;
    un2 = __builtin_elementwise_fma(K1p, m2, nc0);
    d2 = un2 - U0;
    q2v = __builtin_elementwise_fma(d2, d2, q2v);
    U0 = un2;
    // pair 1
    m2.x = __builtin_amdgcn_fmed3f(U1.x, CC, Ch);
    m2.y = __builtin_amdgcn_fmed3f(U1.y, CC, Ch);
    sp += m2;
    un2 = __builtin_elementwise_fma(K1p, m2, nc1);
    d2 = un2 - U1;
    q2v = __builtin_elementwise_fma(d2, d2, q2v);
    U1 = un2;

    v2f red;
    red.x = sp.x + sp.y;
    red.y = q2v.x + q2v.y;
    red = reduce16v(red);                   // {Sm', q2} over the row
    const float s_ = red.x;
    const float q2 = red.y;

    // q1 via row-sum recurrence: sum(U+) = K1*Sm' + Snc
    const float SUn = __builtin_fmaf(K1, s_, Snc);
    const float q1 = SUn - SU;
    SU = SUn;

    const float Sx = 0.05f * __builtin_fmaf(-64.0f, CC, s_);
    const float t_ = __builtin_fmaf(K2, Sx, -R);
    const float corr20 = __builtin_fmaf(t_, 0.3125f, -10.0f);
    R = (R - Sx) + 32.0f;
    const float CCn = __builtin_fmaf(K1, CC, corr20);
    const float dCC = CCn - CC;
    CC = CCn;
    const float a_ = __builtin_fmaf(64.0f, dCC, -2.0f * q1);
    const float ds = __builtin_fmaf(dCC, a_, q2);
    if (__all(ds <= 0.04f)) { ib = i; break; }   // wave-max Tr (4 rows)
  }

  __shared__ int ibs[4];
  if (lane == 0) ibs[wid] = ib;
  __syncthreads();
  if (threadIdx.x == 0) {
    const int m01 = ibs[0] > ibs[1] ? ibs[0] : ibs[1];
    const int m23 = ibs[2] > ibs[3] ? ibs[2] : ibs[3];
    atomicMax(Tsample, m01 > m23 ? m01 : m23);
  }
}

// ===========================================================================
// layout D — 4 lanes/row, 16 elems/lane as 8 NAMED v2f; packed math.
// Macros identical to r16 (proven at the VALU-execution roofline).
// ===========================================================================

#define P8(X) X(0) X(1) X(2) X(3) X(4) X(5) X(6) X(7)

#define PAIRS4(X) X(0,0,1) X(1,2,3) X(2,4,5) X(3,6,7)

#define DECL_STATE(p) v2f U##p, nc##p;

#define PIN(p) asm("" : "+v"(U##p), "+v"(nc##p));

#define LOADC(k, p0, p1) { \
  const float4 cq = *(const float4*)(cost + base + 4 * (k)); \
  nc##p0.x = -cq.x; nc##p0.y = -cq.y; nc##p1.x = -cq.z; nc##p1.y = -cq.w; }

#define INITU(p) { \
  const float za = z0_at((uint32_t)(base + 2 * (p))); \
  const float zb = z0_at((uint32_t)(base + 2 * (p) + 1)); \
  U##p.x = 20.0f * za; U##p.y = 20.0f * zb; \
  r0 = __builtin_fmaf(-0.05f, nc##p.x, r0 + za); \
  r1 = __builtin_fmaf(-0.05f, nc##p.y, r1 + zb); }

#define FSTEP(p) { v2f m2; \
  m2.x = __builtin_amdgcn_fmed3f(U##p.x, CC, Ch); \
  m2.y = __builtin_amdgcn_fmed3f(U##p.y, CC, Ch); \
  if ((p) & 1) spB += m2; else spA += m2; \
  U##p = __builtin_elementwise_fma(K1p, m2, nc##p); }

#define FAST_ITER() { \
  const float Ch = CC + 20.0f; \
  v2f spA = {0.0f, 0.0f}, spB = {0.0f, 0.0f}; \
  P8(FSTEP) \
  const v2f spc = spA + spB; \
  const float s_ = reduce4(spc.x + spc.y); \
  const float Sx = 0.05f * __builtin_fmaf(-64.0f, CC, s_); \
  const float t_ = __builtin_fmaf(K2, Sx, -R); \
  const float corr20 = __builtin_fmaf(t_, 0.3125f, -10.0f); \
  R = (R - Sx) + 32.0f; \
  CC = __builtin_fmaf(K1, CC, corr20); }

#define CSTEP(p) { v2f m2; \
  m2.x = __builtin_amdgcn_fmed3f(U##p.x, CC, Ch); \
  m2.y = __builtin_amdgcn_fmed3f(U##p.y, CC, Ch); \
  if ((p) & 1) spB += m2; else spA += m2; \
  const v2f un2 = __builtin_elementwise_fma(K1p, m2, nc##p); \
  const v2f d2 = un2 - U##p; \
  q1v += d2; \
  q2v = __builtin_elementwise_fma(d2, d2, q2v); \
  U##p = un2; }

#define CHK_ITER(DS) { \
  const float Ch = CC + 20.0f; \
  v2f spA = {0.0f, 0.0f}, spB = {0.0f, 0.0f}; \
  v2f q1v = {0.0f, 0.0f}, q2v = {0.0f, 0.0f}; \
  P8(CSTEP) \
  const v2f spc = spA + spB; \
  const float s_ = reduce4(spc.x + spc.y); \
  const float Sx = 0.05f * __builtin_fmaf(-64.0f, CC, s_); \
  const float t_ = __builtin_fmaf(K2, Sx, -R); \
  const float corr20 = __builtin_fmaf(t_, 0.3125f, -10.0f); \
  R = (R - Sx) + 32.0f; \
  const float CCn = __builtin_fmaf(K1, CC, corr20); \
  const float dCC = CCn - CC; CC = CCn; \
  const float q1 = reduce4(q1v.x + q1v.y); \
  const float q2 = reduce4(q2v.x + q2v.y); \
  const float a_ = __builtin_fmaf(64.0f, dCC, -2.0f * q1); \
  DS = __builtin_fmaf(dCC, a_, q2); }

#define STZ(k, p0, p1) { float4 zq; \
  zq.x = __builtin_fmaf(0.05f, U##p0.x, -CC05); \
  zq.y = __builtin_fmaf(0.05f, U##p0.y, -CC05); \
  zq.z = __builtin_fmaf(0.05f, U##p1.x, -CC05); \
  zq.w = __builtin_fmaf(0.05f, U##p1.y, -CC05); \
  *(float4*)(zst + base + 4 * (k)) = zq; }

#define LOADZ(k, p0, p1) { \
  const float4 zq = *(const float4*)(zst + base + 4 * (k)); \
  U##p0.x = 20.0f * zq.x; U##p0.y = 20.0f * zq.y; \
  U##p1.x = 20.0f * zq.z; U##p1.y = 20.0f * zq.w; \
  r0 += zq.x + zq.y; r1 += zq.z + zq.w; }

#define RC(p) { r0 = __builtin_fmaf(-0.05f, nc##p.x, r0); \
  r1 = __builtin_fmaf(-0.05f, nc##p.y, r1); }

#define STOUT(k, p0, p1) { float4 o; \
  o.x = __builtin_amdgcn_fmed3f( \
      __builtin_fmaf(0.05f, U##p0.x, -CC05), 0.0f, 1.0f); \
  o.y = __builtin_amdgcn_fmed3f( \
      __builtin_fmaf(0.05f, U##p0.y, -CC05), 0.0f, 1.0f); \
  o.z = __builtin_amdgcn_fmed3f( \
      __builtin_fmaf(0.05f, U##p1.x, -CC05), 0.0f, 1.0f); \
  o.w = __builtin_amdgcn_fmed3f( \
      __builtin_fmaf(0.05f, U##p1.y, -CC05), 0.0f, 1.0f); \
  *(float4*)(out + base + 4 * (k)) = o; }

// ===========================================================================
// FUSED kernel — 2048 blocks x 256 thr (8192 waves, exactly 8 blocks/CU),
// 2 row-groups/wave, grid.sync() replaces the pass1/pass2 boundary.
// ===========================================================================
__global__ __attribute__((amdgpu_flat_work_group_size(256, 256),
                          amdgpu_waves_per_eu(8, 8)))
void dys_fused(const float* __restrict__ cost,
               const int* __restrict__ Tsample,
               int* __restrict__ Tglob,
               float* __restrict__ zst,
               float* __restrict__ out) {
  const int lane = threadIdx.x & 63;
  const int gw = blockIdx.x * 4 + (threadIdx.x >> 6);   // 0..8191
  const v2f K1p = {K1, K1};

  const int Ts = *Tsample;                 // uniform (probe done: prior kernel)
  const int Pn = (Ts > 2) ? (Ts - 2) : 0;

  // ---- phase A, group 0: full solve, checkpoint z(ib0), state discarded ---
  int ib0 = MAXIT;
  {
    const int base = (gw * RPW_D + (lane >> 2)) * 64 + (lane & 3) * 16;
    P8(DECL_STATE)
    PAIRS4(LOADC)
    float r0 = 0.0f, r1 = 0.0f;
    P8(INITU)
    P8(PIN)
    float R = reduce4(r0 + r1);
    float CC = 0.0f;
    for (int i = 0; i < Pn; ++i) FAST_ITER();
    for (int i = Pn + 1; i <= MAXIT; ++i) {
      float ds;
      CHK_ITER(ds)
      if (__all(ds <= 0.04f)) { ib0 = i; break; }
    }
    const float CC05 = 0.05f * CC;
    PAIRS4(STZ)                            // same-wave scratch in HBM/L3
  }
  if (lane == 0) atomicMax(Tglob, ib0);

  // ---- phase A, group 1: full solve, state KEPT IN REGISTERS -------------
  P8(DECL_STATE)                           // outer: survives grid.sync()
  float CC = 0.0f, R;
  int ib1 = MAXIT;
  {
    const int base = ((FUSED_WAVES + gw) * RPW_D + (lane >> 2)) * 64 +
                     (lane & 3) * 16;
    PAIRS4(LOADC)
    float r0 = 0.0f, r1 = 0.0f;
    P8(INITU)
    P8(PIN)
    R = reduce4(r0 + r1);
  }
  for (int i = 0; i < Pn; ++i) FAST_ITER();
  for (int i = Pn + 1; i <= MAXIT; ++i) {
    float ds;
    CHK_ITER(ds)
    if (__all(ds <= 0.04f)) { ib1 = i; break; }
  }
  if (lane == 0) atomicMax(Tglob, ib1);

  // ---- grid barrier: T becomes final -------------------------------------
  cg::this_grid().sync();
  const int T = *Tglob;                    // uniform

  // ---- phase B, group 1: finish fully in-register, store ------------------
  for (int i = ib1; i <= T; ++i) FAST_ITER();   // incl. differentiable step
  {
    const int base = ((FUSED_WAVES + gw) * RPW_D + (lane >> 2)) * 64 +
                     (lane & 3) * 16;
    const float CC05 = 0.05f * CC;
    PAIRS4(STOUT)
  }

  // ---- phase B, group 0: reload checkpoint, finish, store -----------------
  {
    const int base = (gw * RPW_D + (lane >> 2)) * 64 + (lane & 3) * 16;
    PAIRS4(LOADC)
    float r0 = 0.0f, r1 = 0.0f;
    PAIRS4(LOADZ)
    P8(RC)
    P8(PIN)
    R = reduce4(r0 + r1);
    CC = 0.0f;                             // CC-rebase (z is the true state)
    for (int i = ib0; i <= T; ++i) FAST_ITER();
    const float CC05 = 0.05f * CC;
    PAIRS4(STOUT)
  }
}

// ===========================================================================
// FALLBACK path — r16 pass1/pass2, launched only if cooperative launch fails
// ===========================================================================
__global__ __attribute__((amdgpu_flat_work_group_size(256, 256),
                          amdgpu_waves_per_eu(4, 8)))
void dys_pass1(
    const float* __restrict__ cost, const int* __restrict__ Tsample,
    int* __restrict__ Tglob, int* __restrict__ TrArr,
    float* __restrict__ zst) {
  const int lane = threadIdx.x & 63;
  const int gw = blockIdx.x * 4 + (threadIdx.x >> 6);
  const int base = (gw * RPW_D + (lane >> 2)) * 64 + (lane & 3) * 16;

  const v2f K1p = {K1, K1};
  P8(DECL_STATE)
  PAIRS4(LOADC)
  float r0 = 0.0f, r1 = 0.0f;
  P8(INITU)
  P8(PIN)
  float R = reduce4(r0 + r1);
  float CC = 0.0f;

  const int Ts = *Tsample;
  const int Pn = (Ts > 2) ? (Ts - 2) : 0;

  for (int i = 0; i < Pn; ++i) FAST_ITER();

  int ib = MAXIT;
  for (int i = Pn + 1; i <= MAXIT; ++i) {
    float ds;
    CHK_ITER(ds)
    if (__all(ds <= 0.04f)) { ib = i; break; }
  }

  const float CC05 = 0.05f * CC;
  PAIRS4(STZ)
  if (lane == 0) {
    TrArr[gw] = ib;
    atomicMax(Tglob, ib);
  }
}

__global__ __attribute__((amdgpu_flat_work_group_size(256, 256),
                          amdgpu_waves_per_eu(4, 8)))
void dys_pass2(
    const float* __restrict__ cost, const int* __restrict__ Tglob,
    const int* __restrict__ TrArr, const float* __restrict__ zst,
    float* __restrict__ out) {
  const int lane = threadIdx.x & 63;
  const int gw = blockIdx.x * 4 + (threadIdx.x >> 6);
  const int base = (gw * RPW_D + (lane >> 2)) * 64 + (lane & 3) * 16;

  const v2f K1p = {K1, K1};
  P8(DECL_STATE)
  PAIRS4(LOADC)
  float r0 = 0.0f, r1 = 0.0f;
  PAIRS4(LOADZ)
  P8(RC)
  P8(PIN)
  float R = reduce4(r0 + r1);
  float CC = 0.0f;

  const int T = *Tglob;
  const int ib = TrArr[gw];

  for (int i = ib; i <= T; ++i) FAST_ITER();

  const float CC05 = 0.05f * CC;
  PAIRS4(STOUT)
}

extern "C" void kernel_launch(void* const* d_in, const int* in_sizes, int n_in,
                              void* d_out, int out_size, void* d_ws,
                              size_t ws_size, hipStream_t stream) {
  const float* cost = (const float*)d_in[0];
  float* out = (float*)d_out;

  // ws: [0..4) Tglob ; [4..8) Tsample ; [1024..) TrArr ; then z ckpt
  int* Tglob   = (int*)d_ws;
  int* Tsample = (int*)d_ws + 1;
  const size_t TR_OFF = 1024;
  const size_t Z_OFF  = TR_OFF + (size_t)NWAVES_A * sizeof(int);  // 16B-aligned
  int*   TrArr = (int*)((char*)d_ws + TR_OFF);
  float* zst   = (float*)((char*)d_ws + Z_OFF);

  hipMemsetAsync(d_ws, 0, 8, stream);   // Tglob = Tsample = 0

  dim3 block(256);
  dys_probe<<<dim3(PROBE_WAVES_P / 4), block, 0, stream>>>(cost, Tsample);

  const int* TsampleC = Tsample;
  void* kargs[] = {(void*)&cost, (void*)&TsampleC, (void*)&Tglob,
                   (void*)&zst, (void*)&out};
  hipError_t ce = hipLaunchCooperativeKernel(
      (const void*)dys_fused, dim3(FUSED_BLOCKS), block, kargs, 0, stream);
  if (ce != hipSuccess) {
    (void)hipGetLastError();              // clear sticky error, take fallback
    dys_pass1<<<dim3(NWAVES_D / 4), block, 0, stream>>>(cost, Tsample, Tglob,
                                                        TrArr, zst);
    dys_pass2<<<dim3(NWAVES_D / 4), block, 0, stream>>>(cost, Tglob, TrArr,
                                                        zst, out);
  }
}

// Round 9
// 368.373 us; speedup vs baseline: 1.4044x; 1.4044x over previous
//
#include <hip/hip_runtime.h>
#include <cstdint>

// ---------------------------------------------------------------------------
// dysOpt: Davis-Yin splitting, 262144 rows x 64 vars, dynamic T.
//
// x20 u-space iteration (U = 20*(z + C), CC = 20*C):
//   m'  = med3(U, CC, CC+20)      (= 20*(clamp(z,0,1)+C)), computed IN PLACE
//   U+  = K1*m' + nc[j]           (nc = -c, stored negated)
//   Sx  = 0.05*(Sm' - 64*CC) ; t = K2*Sx - R
//   corr20 = t*(20/64) - 10 ; R+ = R - Sx + 32 ; CC+ = K1*CC + corr20
// Exact algebra vs reference; rescale rounding ~1 ulp/iter damped by the
// K1 = 0.9975 contraction.
//
// ROUND-19 (REVERT to r17; r18 post-mortem):
//  * r18 cooperative fusion FAILED: 431us fused (VALUBusy 59). cg grid.sync
//    at 2048 blocks = single-cacheline atomic + spin across 8 non-coherent
//    XCD L2s; static 2-group assignment loses pass1's block-refill
//    pipelining; phase-B latency-exposed. Falsified; reverted.
//  * Cross-round budget now CLOSES: fixed harness/graph overhead ~71us
//    (517-431-15 in r8; invariant across 3-vs-4 dispatch structures),
//    pass1 = 237us AT the VALU-issue roofline (VALUBusy 103, 2 instr/elem
//    minimum: med3 has no packed form, no f32 MFMA for the row-sum),
//    pass2 ~46us (~40 floor: 200MB traffic + resume iters), probe ~15.
//    Structural floor ~364; this kernel measured 369.35 (r7). At roofline.
//
// Structure: probe (8192 rows, checked every iter) -> Ts = max Tr <= T;
// pass1: P = Ts-2 unchecked iters, then checked to wave all-pass = ib
// (residual monotone per row => ib = max(P+1, wave-max Tr) <= T, the argmax
// wave reports exactly T); checkpoint z(ib), atomicMax T.
// pass2: resume ib -> T, +1 differentiable step, clamp, store.
// Check (per row): 400*||dz||^2 = q2 - 2*dCC*q1 + 64*dCC^2 <= 0.04.
// ---------------------------------------------------------------------------

#ifndef JAX_PARTITIONABLE
#define JAX_PARTITIONABLE 1
#endif

#define BATCHN 262144
#define MAXIT  200

#define PROBE_ROWS 8192
// probe layout P: 4 rows/wave, 16 lanes/row, 4 elems/lane
#define RPW_P  4
#define PROBE_WAVES_P (PROBE_ROWS / RPW_P)  // 2048

#define NWAVES_A 16384                      // workspace offset compat (r10)

// layout D (pass1/pass2): 16 rows/wave, 4 lanes/row, 16 elems/lane, pk math
#define RPW_D  16
#define NWAVES_D (BATCHN / RPW_D)           // 16384

#define K1 0.9975f   // 1 - a^2
#define K2 1.9975f   // 2 - a^2

typedef float v2f __attribute__((ext_vector_type(2)));

__device__ __forceinline__ void tf2x32(uint32_t x0, uint32_t x1,
                                       uint32_t& o0, uint32_t& o1) {
  const uint32_t k0 = 0u, k1 = 1u;                 // jax.random.key(1) -> [0,1]
  const uint32_t k2 = 0x1BD11BDAu ^ k0 ^ k1;
  x0 += k0; x1 += k1;
#define TFR(r) { x0 += x1; x1 = (x1 << (r)) | (x1 >> (32 - (r))); x1 ^= x0; }
  TFR(13) TFR(15) TFR(26) TFR(6)   x0 += k1; x1 += k2 + 1u;
  TFR(17) TFR(29) TFR(16) TFR(24)  x0 += k2; x1 += k0 + 2u;
  TFR(13) TFR(15) TFR(26) TFR(6)   x0 += k0; x1 += k1 + 3u;
  TFR(17) TFR(29) TFR(16) TFR(24)  x0 += k1; x1 += k2 + 4u;
  TFR(13) TFR(15) TFR(26) TFR(6)   x0 += k2; x1 += k0 + 5u;
#undef TFR
  o0 = x0; o1 = x1;
}

__device__ __forceinline__ float z0_at(uint32_t f) {
  uint32_t b;
#if JAX_PARTITIONABLE
  uint32_t o0, o1;
  tf2x32(0u, f, o0, o1);
  b = o0 ^ o1;
#else
  const uint32_t H = 8388608u;
  uint32_t lo = (f < H) ? f : (f - H);
  uint32_t o0, o1;
  tf2x32(lo, lo + H, o0, o1);
  b = (f < H) ? o0 : o1;
#endif
  return __uint_as_float((b >> 9) | 0x3f800000u) - 1.0f;
}

// DPP cross-lane add: v += v(lane DPP-selected). Pure VALU.
template <int CTRL>
__device__ __forceinline__ float dpp_add(float v) {
  int s = __builtin_amdgcn_mov_dpp(__float_as_int(v), CTRL, 0xF, 0xF, true);
  return v + __int_as_float(s);
}

// 4-lane row reduction (row = one quad), all-VALU (layout D)
__device__ __forceinline__ float reduce4(float v) {
  v = dpp_add<0xB1>(v);    // quad_perm [1,0,3,2] : xor 1
  v = dpp_add<0x4E>(v);    // quad_perm [2,3,0,1] : xor 2
  return v;
}

// packed DPP add for a v2f (two mov_dpp + one pk_add)
template <int CTRL>
__device__ __forceinline__ v2f dpp_addv(v2f v) {
  int sx = __builtin_amdgcn_mov_dpp(__float_as_int(v.x), CTRL, 0xF, 0xF, true);
  int sy = __builtin_amdgcn_mov_dpp(__float_as_int(v.y), CTRL, 0xF, 0xF, true);
  v2f s;
  s.x = __int_as_float(sx);
  s.y = __int_as_float(sy);
  return v + s;
}

// 16-lane row sum of BOTH v2f components (probe): xor1, xor2, ror4, ror8.
// After xor1+xor2 each quad holds its 4-sum; rotations by 4 then 8 within
// the 16-lane DPP row complete the commutative sum in every lane.
__device__ __forceinline__ v2f reduce16v(v2f v) {
  v = dpp_addv<0xB1>(v);     // quad_perm xor 1
  v = dpp_addv<0x4E>(v);     // quad_perm xor 2
  v = dpp_addv<0x124>(v);    // row_ror:4
  v = dpp_addv<0x128>(v);    // row_ror:8
  return v;
}

// ===========================================================================
// probe — 2048 waves (2/SIMD), packed math, single packed reduction/iter
// ===========================================================================
__global__ __launch_bounds__(256, 4) void dys_probe(
    const float* __restrict__ cost, int* __restrict__ Tsample) {
  const int lane = threadIdx.x & 63;
  const int wid  = threadIdx.x >> 6;
  const int gw = blockIdx.x * 4 + wid;
  const int base = (gw * RPW_P + (lane >> 4)) * 64 + (lane & 15) * 4;

  const v2f K1p = {K1, K1};
  const float4 cq = *(const float4*)(cost + base);
  v2f nc0, nc1;
  nc0.x = -cq.x; nc0.y = -cq.y; nc1.x = -cq.z; nc1.y = -cq.w;

  const float z0 = z0_at((uint32_t)(base + 0));
  const float z1 = z0_at((uint32_t)(base + 1));
  const float z2 = z0_at((uint32_t)(base + 2));
  const float z3 = z0_at((uint32_t)(base + 3));
  v2f U0, U1;
  U0.x = 20.0f * z0; U0.y = 20.0f * z1;
  U1.x = 20.0f * z2; U1.y = 20.0f * z3;

  v2f zc;                                   // {Sz partial, Sc partial}
  zc.x = (z0 + z1) + (z2 + z3);
  zc.y = (cq.x + cq.y) + (cq.z + cq.w);
  zc = reduce16v(zc);                       // {Sz, Sc} over the row
  float R   = __builtin_fmaf(0.05f, zc.y, zc.x);   // Sz + a*Sc
  const float Snc = -zc.y;                  // sum of nc over the row
  float SU  = 20.0f * zc.x;                 // sum of U over the row
  float CC = 0.0f;

  int ib = MAXIT;
  for (int i = 1; i <= MAXIT; ++i) {
    const float Ch = CC + 20.0f;
    v2f sp, q2v = {0.0f, 0.0f};
    v2f m2, un2, d2;
    // pair 0
    m2.x = __builtin_amdgcn_fmed3f(U0.x, CC, Ch);
    m2.y = __builtin_amdgcn_fmed3f(U0.y, CC, Ch);
    sp = m2;
    un2 = __builtin_elementwise_fma(K1p, m2, nc0);
    d2 = un2 - U0;
    q2v = __builtin_elementwise_fma(d2, d2, q2v);
    U0 = un2;
    // pair 1
    m2.x = __builtin_amdgcn_fmed3f(U1.x, CC, Ch);
    m2.y = __builtin_amdgcn_fmed3f(U1.y, CC, Ch);
    sp += m2;
    un2 = __builtin_elementwise_fma(K1p, m2, nc1);
    d2 = un2 - U1;
    q2v = __builtin_elementwise_fma(d2, d2, q2v);
    U1 = un2;

    v2f red;
    red.x = sp.x + sp.y;
    red.y = q2v.x + q2v.y;
    red = reduce16v(red);                   // {Sm', q2} over the row
    const float s_ = red.x;
    const float q2 = red.y;

    // q1 = sum(d) via the row-sum recurrence (no third reduction):
    // sum(U+) = K1*Sm' + Snc
    const float SUn = __builtin_fmaf(K1, s_, Snc);
    const float q1 = SUn - SU;
    SU = SUn;

    const float Sx = 0.05f * __builtin_fmaf(-64.0f, CC, s_);
    const float t_ = __builtin_fmaf(K2, Sx, -R);
    const float corr20 = __builtin_fmaf(t_, 0.3125f, -10.0f);
    R = (R - Sx) + 32.0f;
    const float CCn = __builtin_fmaf(K1, CC, corr20);
    const float dCC = CCn - CC;
    CC = CCn;
    const float a_ = __builtin_fmaf(64.0f, dCC, -2.0f * q1);
    const float ds = __builtin_fmaf(dCC, a_, q2);
    if (__all(ds <= 0.04f)) { ib = i; break; }   // wave-max Tr (4 rows)
  }

  __shared__ int ibs[4];
  if (lane == 0) ibs[wid] = ib;
  __syncthreads();
  if (threadIdx.x == 0) {
    const int m01 = ibs[0] > ibs[1] ? ibs[0] : ibs[1];
    const int m23 = ibs[2] > ibs[3] ? ibs[2] : ibs[3];
    atomicMax(Tsample, m01 > m23 ? m01 : m23);
  }
}

// ===========================================================================
// layout D — 4 lanes/row, 16 elems/lane as 8 NAMED v2f; packed math.
// BYTE-IDENTICAL to r16 (proven at the VALU-execution roofline).
// ===========================================================================

#define P8(X) X(0) X(1) X(2) X(3) X(4) X(5) X(6) X(7)

#define PAIRS4(X) X(0,0,1) X(1,2,3) X(2,4,5) X(3,6,7)

// state declaration: U0..U7, nc0..nc7 (each v2f = one even-aligned VGPR pair)
#define DECL_STATE(p) v2f U##p, nc##p;

// pin whole v2f (64-bit "v" operand) — blocks remat-reload (r10 lesson)
#define PIN(p) asm("" : "+v"(U##p), "+v"(nc##p));

// load cost, negated: nc = -c
#define LOADC(k, p0, p1) { \
  const float4 cq = *(const float4*)(cost + base + 4 * (k)); \
  nc##p0.x = -cq.x; nc##p0.y = -cq.y; nc##p1.x = -cq.z; nc##p1.y = -cq.w; }

// init U from threefry z0; accumulate R partials
#define INITU(p) { \
  const float za = z0_at((uint32_t)(base + 2 * (p))); \
  const float zb = z0_at((uint32_t)(base + 2 * (p) + 1)); \
  U##p.x = 20.0f * za; U##p.y = 20.0f * zb; \
  r0 = __builtin_fmaf(-0.05f, nc##p.x, r0 + za); \
  r1 = __builtin_fmaf(-0.05f, nc##p.y, r1 + zb); }

// fast step: 2 med3 + 1 pk_add + 1 pk_fma per pair
#define FSTEP(p) { v2f m2; \
  m2.x = __builtin_amdgcn_fmed3f(U##p.x, CC, Ch); \
  m2.y = __builtin_amdgcn_fmed3f(U##p.y, CC, Ch); \
  if ((p) & 1) spB += m2; else spA += m2; \
  U##p = __builtin_elementwise_fma(K1p, m2, nc##p); }

#define FAST_ITER() { \
  const float Ch = CC + 20.0f; \
  v2f spA = {0.0f, 0.0f}, spB = {0.0f, 0.0f}; \
  P8(FSTEP) \
  const v2f spc = spA + spB; \
  const float s_ = reduce4(spc.x + spc.y); \
  const float Sx = 0.05f * __builtin_fmaf(-64.0f, CC, s_); \
  const float t_ = __builtin_fmaf(K2, Sx, -R); \
  const float corr20 = __builtin_fmaf(t_, 0.3125f, -10.0f); \
  R = (R - Sx) + 32.0f; \
  CC = __builtin_fmaf(K1, CC, corr20); }

// checked step: adds d, d^2 accumulation
#define CSTEP(p) { v2f m2; \
  m2.x = __builtin_amdgcn_fmed3f(U##p.x, CC, Ch); \
  m2.y = __builtin_amdgcn_fmed3f(U##p.y, CC, Ch); \
  if ((p) & 1) spB += m2; else spA += m2; \
  const v2f un2 = __builtin_elementwise_fma(K1p, m2, nc##p); \
  const v2f d2 = un2 - U##p; \
  q1v += d2; \
  q2v = __builtin_elementwise_fma(d2, d2, q2v); \
  U##p = un2; }

#define CHK_ITER(DS) { \
  const float Ch = CC + 20.0f; \
  v2f spA = {0.0f, 0.0f}, spB = {0.0f, 0.0f}; \
  v2f q1v = {0.0f, 0.0f}, q2v = {0.0f, 0.0f}; \
  P8(CSTEP) \
  const v2f spc = spA + spB; \
  const float s_ = reduce4(spc.x + spc.y); \
  const float Sx = 0.05f * __builtin_fmaf(-64.0f, CC, s_); \
  const float t_ = __builtin_fmaf(K2, Sx, -R); \
  const float corr20 = __builtin_fmaf(t_, 0.3125f, -10.0f); \
  R = (R - Sx) + 32.0f; \
  const float CCn = __builtin_fmaf(K1, CC, corr20); \
  const float dCC = CCn - CC; CC = CCn; \
  const float q1 = reduce4(q1v.x + q1v.y); \
  const float q2 = reduce4(q2v.x + q2v.y); \
  const float a_ = __builtin_fmaf(64.0f, dCC, -2.0f * q1); \
  DS = __builtin_fmaf(dCC, a_, q2); }

// store z checkpoint: z = 0.05*U - 0.05*CC
#define STZ(k, p0, p1) { float4 zq; \
  zq.x = __builtin_fmaf(0.05f, U##p0.x, -CC05); \
  zq.y = __builtin_fmaf(0.05f, U##p0.y, -CC05); \
  zq.z = __builtin_fmaf(0.05f, U##p1.x, -CC05); \
  zq.w = __builtin_fmaf(0.05f, U##p1.y, -CC05); \
  *(float4*)(zst + base + 4 * (k)) = zq; }

// pass2: load z checkpoint, accumulate R partials
#define LOADZ(k, p0, p1) { \
  const float4 zq = *(const float4*)(zst + base + 4 * (k)); \
  U##p0.x = 20.0f * zq.x; U##p0.y = 20.0f * zq.y; \
  U##p1.x = 20.0f * zq.z; U##p1.y = 20.0f * zq.w; \
  r0 += zq.x + zq.y; r1 += zq.z + zq.w; }

// pass2: R += 0.05*c
#define RC(p) { r0 = __builtin_fmaf(-0.05f, nc##p.x, r0); \
  r1 = __builtin_fmaf(-0.05f, nc##p.y, r1); }

// final store: clamp(z, 0, 1)
#define STOUT(k, p0, p1) { float4 o; \
  o.x = __builtin_amdgcn_fmed3f( \
      __builtin_fmaf(0.05f, U##p0.x, -CC05), 0.0f, 1.0f); \
  o.y = __builtin_amdgcn_fmed3f( \
      __builtin_fmaf(0.05f, U##p0.y, -CC05), 0.0f, 1.0f); \
  o.z = __builtin_amdgcn_fmed3f( \
      __builtin_fmaf(0.05f, U##p1.x, -CC05), 0.0f, 1.0f); \
  o.w = __builtin_amdgcn_fmed3f( \
      __builtin_fmaf(0.05f, U##p1.y, -CC05), 0.0f, 1.0f); \
  *(float4*)(out + base + 4 * (k)) = o; }

// --- pass1: P unchecked iters, checked to wave all-pass; checkpoint --------
__global__ __attribute__((amdgpu_flat_work_group_size(256, 256),
                          amdgpu_waves_per_eu(4, 8)))
void dys_pass1(
    const float* __restrict__ cost, const int* __restrict__ Tsample,
    int* __restrict__ Tglob, int* __restrict__ TrArr,
    float* __restrict__ zst) {
  const int lane = threadIdx.x & 63;
  const int gw = blockIdx.x * 4 + (threadIdx.x >> 6);
  const int base = (gw * RPW_D + (lane >> 2)) * 64 + (lane & 3) * 16;

  const v2f K1p = {K1, K1};
  P8(DECL_STATE)
  PAIRS4(LOADC)
  float r0 = 0.0f, r1 = 0.0f;
  P8(INITU)
  P8(PIN)
  float R = reduce4(r0 + r1);              // R = Sz + a*Sc over the row
  float CC = 0.0f;

  const int Ts = *Tsample;                 // uniform
  const int Pn = (Ts > 2) ? (Ts - 2) : 0;  // P+1 <= Ts <= T

  for (int i = 0; i < Pn; ++i) FAST_ITER();

  int ib = MAXIT;
  for (int i = Pn + 1; i <= MAXIT; ++i) {
    float ds;
    CHK_ITER(ds)
    if (__all(ds <= 0.04f)) { ib = i; break; }
  }
  // ib = max(Pn+1, wave-max Tr) <= T; the argmax wave reports exactly T.

  const float CC05 = 0.05f * CC;           // z = 0.05*U - 0.05*CC
  PAIRS4(STZ)
  if (lane == 0) {
    TrArr[gw] = ib;
    atomicMax(Tglob, ib);
  }
}

// --- pass2: resume ib -> T, +1 differentiable step, clamp, store -----------
__global__ __attribute__((amdgpu_flat_work_group_size(256, 256),
                          amdgpu_waves_per_eu(4, 8)))
void dys_pass2(
    const float* __restrict__ cost, const int* __restrict__ Tglob,
    const int* __restrict__ TrArr, const float* __restrict__ zst,
    float* __restrict__ out) {
  const int lane = threadIdx.x & 63;
  const int gw = blockIdx.x * 4 + (threadIdx.x >> 6);
  const int base = (gw * RPW_D + (lane >> 2)) * 64 + (lane & 3) * 16;

  const v2f K1p = {K1, K1};
  P8(DECL_STATE)
  PAIRS4(LOADC)
  float r0 = 0.0f, r1 = 0.0f;
  PAIRS4(LOADZ)
  P8(RC)
  P8(PIN)
  float R = reduce4(r0 + r1);              // R = Sz + a*Sc (invariant)
  float CC = 0.0f;

  const int T = *Tglob;
  const int ib = TrArr[gw];                // wave-uniform

  // (T - ib) lockstep iters to z(T), +1 differentiable step
  for (int i = ib; i <= T; ++i) FAST_ITER();

  const float CC05 = 0.05f * CC;
  PAIRS4(STOUT)
}

extern "C" void kernel_launch(void* const* d_in, const int* in_sizes, int n_in,
                              void* d_out, int out_size, void* d_ws,
                              size_t ws_size, hipStream_t stream) {
  const float* cost = (const float*)d_in[0];
  float* out = (float*)d_out;

  // ws: [0..4) Tglob ; [4..8) Tsample ; [1024..) TrArr ; then z ckpt
  // (offsets kept from r10: TrArr region sized for 16384 ints; D uses 16384)
  int* Tglob   = (int*)d_ws;
  int* Tsample = (int*)d_ws + 1;
  const size_t TR_OFF = 1024;
  const size_t Z_OFF  = TR_OFF + (size_t)NWAVES_A * sizeof(int);  // 16B-aligned
  int*   TrArr = (int*)((char*)d_ws + TR_OFF);
  float* zst   = (float*)((char*)d_ws + Z_OFF);

  hipMemsetAsync(d_ws, 0, 8, stream);   // Tglob = Tsample = 0

  dim3 block(256);
  dys_probe<<<dim3(PROBE_WAVES_P / 4), block, 0, stream>>>(cost, Tsample);
  dys_pass1<<<dim3(NWAVES_D / 4), block, 0, stream>>>(cost, Tsample, Tglob,
                                                      TrArr, zst);
  dys_pass2<<<dim3(NWAVES_D / 4), block, 0, stream>>>(cost, Tglob, TrArr, zst,
                                                      out);
}